// Round 4
// baseline (1687.355 us; speedup 1.0000x reference)
//
#include <hip/hip_runtime.h>
#include <math.h>

#define NN    6144
#define MP1   6145
#define FINF  99999.0f

// ---- phase 1: boundary-only systolic chain (R=KC=8, diagonal-ILP step) ----
#define R1     8                 // rows per lane per step
#define KC1    8                 // columns per lane
#define WCH1   (KC1 * 64)        // 512 cols per wave
#define GCH1   (NN / WCH1)       // 12 strips
#define RTS1   8                 // steps per flag (= 64 boundary rows)
#define NWS1   (NN / R1)         // 768 work steps
#define STEPS1 (NWS1 + 63)       // 831 incl. lane stagger

// ---- phase 2: independent tiles (KC=8 to match 512-col strips) ----
#define R2     4
#define KC2    8
#define WCH2   (KC2 * 64)        // 512 cols per tile
#define BR     384               // rows per band
#define NBI    (NN / BR)         // 16 bands
#define TS2    (BR / R2)         // 96 work steps
#define STEPS2 (TS2 + 63)        // 159

typedef float f4a __attribute__((ext_vector_type(4), aligned(4)));   // unaligned-ok store
typedef float f4v __attribute__((ext_vector_type(4), aligned(16)));  // aligned vec

__device__ __forceinline__ float readlane_f(float v, int l) {
    return __int_as_float(__builtin_amdgcn_readlane(__float_as_int(v), l));
}
// lane i <- lane i-1, via DPP wave_shr:1 (VALU-speed)
__device__ __forceinline__ float shup1(float v) {
    return __int_as_float(__builtin_amdgcn_update_dpp(
        0, __float_as_int(v), 0x138, 0xF, 0xF, false));
}

// ============================ PHASE 1 ============================
// Lane-systolic DTW, 8x8 cells per lane per step, stores ONLY boundaries.
// Step body emitted as a DIAGONAL WAVEFRONT over (r+q): cells on a diagonal
// are independent -> chain depth 15 cells (min3+add each) instead of 64.
// rv[r] = running row value (left neighbor), rd[r] = value one diagonal back
// (diag neighbor for row r+1). cur[] holds the row above (updated by row 7).
// Identical operand sets per cell (min assoc/comm) -> bit-identical results.
__global__ void __launch_bounds__(64) dtw_bnd(const float* __restrict__ x,
                                              const float* __restrict__ y,
                                              int* __restrict__ flags,
                                              float* __restrict__ bnd,
                                              float* __restrict__ rowb) {
    const int g    = blockIdx.x;
    const int lane = threadIdx.x;
    const int c0   = g * WCH1 + lane * KC1;

    float yv[KC1], cur[KC1];
#pragma unroll
    for (int q = 0; q < KC1; ++q) {
        yv[q]  = y[c0 + q];
        cur[q] = FINF;                   // dtw[0][col] = INF
    }
    float pl = (c0 == 0) ? 0.0f : FINF;  // diag seed: dtw[0][0] = 0
    float rowval[R1];                    // persists as rlast across steps
#pragma unroll
    for (int r = 0; r < R1; ++r) rowval[r] = FINF;
    float vbuf = FINF, vnext = FINF;

    // x register window: per 64-step window w, lane m holds x[8*(64w+m) .. +7]
    const float4* x4 = (const float4*)x;
    float4 xwA  = x4[2 * lane];
    float4 xwB  = x4[2 * lane + 1];
    float4 xwAN = x4[2 * (64 + lane)];
    float4 xwBN = x4[2 * (64 + lane) + 1];
    float xcur[R1];
#pragma unroll
    for (int r = 0; r < R1; ++r) xcur[r] = x[r];

    // ---- prefetch tile 0 boundary (rows 0..63) before the loop ----
    if (g != 0) {
        while (__hip_atomic_load(&flags[(g - 1) * 16], __ATOMIC_ACQUIRE,
                                 __HIP_MEMORY_SCOPE_AGENT) < 1) {
            __builtin_amdgcn_s_sleep(1);
        }
        vnext = bnd[(size_t)(g - 1) * NN + lane];
    }

    for (int s = 0; s < STEPS1; ++s) {
        // ---- producer publish (top of step, >=1 full step of store slack) ----
        if (g != GCH1 - 1 && s > 64 && ((s - 64) & (RTS1 - 1)) == 0) {
            if (lane == 0)
                __hip_atomic_store(&flags[g * 16], (s - 64) >> 3,
                                   __ATOMIC_RELEASE, __HIP_MEMORY_SCOPE_AGENT);
        }

        // ---- consume the prefetched boundary window ----
        if (g != 0 && s < NWS1 && (s & (RTS1 - 1)) == 0) vbuf = vnext;

        // ---- prefetch next window's 64 boundary rows, 4 steps early ----
        if (g != 0 && (s & (RTS1 - 1)) == RTS1 - 4 && (s + 4) < NWS1) {
            const int want = ((s + 4) >> 3) + 1;
            while (__hip_atomic_load(&flags[(g - 1) * 16], __ATOMIC_ACQUIRE,
                                     __HIP_MEMORY_SCOPE_AGENT) < want) {
                __builtin_amdgcn_s_sleep(1);
            }
            vnext = bnd[(size_t)(g - 1) * NN + (size_t)R1 * (s + 4) + lane];
        }

        // ---- carries: DPP wave_shr1 of last step's right edges ----
        float vin[R1];
#pragma unroll
        for (int r = 0; r < R1; ++r) {
            const float up = shup1(rowval[r]);
            const float vb = readlane_f(vbuf, ((s & (RTS1 - 1)) << 3) + r);
            const float l0 = (g == 0) ? FINF : vb;
            vin[r] = (lane == 0) ? l0 : up;
        }

        const int  t      = s - lane;
        const bool active = (t >= 0) && (t < NWS1);
        if (active) {
            float rv[R1], rd[R1];
#pragma unroll
            for (int r = 0; r < R1; ++r) rv[r] = vin[r];

            // ---- diagonal wavefront: d = r + q, rows processed DESCENDING so
            // row r reads rv/rd[r-1] from diagonal d-1 before row r-1 updates.
#pragma unroll
            for (int d = 0; d < R1 + KC1 - 1; ++d) {
#pragma unroll
                for (int r = R1 - 1; r >= 0; --r) {
                    const int q = d - r;
                    if (q < 0 || q >= KC1) continue;
                    const float up = (r == 0) ? cur[q] : rv[r - 1];
                    const float dg = (r == 0) ? ((q == 0) ? pl : cur[q - 1])
                                              : rd[r - 1];
                    const float dx = xcur[r] - yv[q];
                    const float nv = dx * dx + fminf(fminf(up, dg), rv[r]);
                    rd[r] = rv[r];
                    rv[r] = nv;
                    if (r == R1 - 1) cur[q] = nv;   // row above for next step
                }
            }
#pragma unroll
            for (int r = 0; r < R1; ++r) rowval[r] = rv[r];
            pl = vin[R1 - 1];

            // band top rows: row 384k is r=7 of work step t=48k-1 (== cur[])
            {
                const int tp1 = t + 1;
                const int k   = tp1 / 48;
                if (k * 48 == tp1 && k >= 1 && k <= NBI - 1) {
                    *(f4a*)&rowb[(size_t)k * MP1 + c0 + 1] =
                        (f4a){cur[0], cur[1], cur[2], cur[3]};
                    *(f4a*)&rowb[(size_t)k * MP1 + c0 + 5] =
                        (f4a){cur[4], cur[5], cur[6], cur[7]};
                }
            }
            if (lane == 63) {
                *(f4v*)&bnd[(size_t)g * NN + (size_t)R1 * t] =
                    (f4v){rowval[0], rowval[1], rowval[2], rowval[3]};
                *(f4v*)&bnd[(size_t)g * NN + (size_t)R1 * t + 4] =
                    (f4v){rowval[4], rowval[5], rowval[6], rowval[7]};
            }
        }

        // ---- x for next step (off the carry chain) ----
        const int sn = s + 1;
        if ((sn & 63) == 0) {
            xwA = xwAN;
            xwB = xwBN;
            int nb = sn + 64 + lane;                 // float8-unit index
            if (nb > NN / 8 - 1) nb = NN / 8 - 1;
            xwAN = x4[2 * nb];
            xwBN = x4[2 * nb + 1];
        }
        const float* xap = (const float*)&xwA;
        const float* xbp = (const float*)&xwB;
#pragma unroll
        for (int r = 0; r < 4; ++r) {
            const float xs = shup1(xcur[r]);
            const float xj = readlane_f(xap[r], sn & 63);
            xcur[r] = (lane == 0) ? xj : xs;
        }
#pragma unroll
        for (int r = 4; r < 8; ++r) {
            const float xs = shup1(xcur[r]);
            const float xj = readlane_f(xbp[r - 4], sn & 63);
            xcur[r] = (lane == 0) ? xj : xs;
        }
    }

    // final window flag (w = 96) — produced by the last loop steps
    if (g != GCH1 - 1 && lane == 0) {
        __hip_atomic_store(&flags[g * 16], NWS1 >> 3,
                           __ATOMIC_RELEASE, __HIP_MEMORY_SCOPE_AGENT);
    }
}

// ============================ PHASE 2 ============================
// 192 independent 384-row x 512-col tiles seeded from bnd/rowb; same
// diagonal-wavefront step body; sqrt fused into coalesced stores to out.
__global__ void __launch_bounds__(64) dtw_tile(const float* __restrict__ x,
                                               const float* __restrict__ y,
                                               const float* __restrict__ bnd,
                                               const float* __restrict__ rowb,
                                               float* __restrict__ out) {
    const int bj   = blockIdx.x;         // strip  (column block, 0..11)
    const int bi   = blockIdx.y;         // band   (row block,    0..15)
    const int lane = threadIdx.x;

    __shared__ float left_s[BR];         // left boundary col, rows +1..+384
    __shared__ float top_s[WCH2 + 1];    // top boundary row, local cols 0..512
    __shared__ float xb_s[BR];           // x for this band

#pragma unroll
    for (int k = 0; k < BR / 64; ++k) {
        const int i = 64 * k + lane;     // 0..383
        left_s[i] = (bj == 0) ? FINF
                              : bnd[(size_t)(bj - 1) * NN + BR * bi + i];
        xb_s[i] = x[BR * bi + i];
    }
    for (int c = lane; c < WCH2 + 1; c += 64) {
        float tv;
        if (bi == 0)                tv = (bj == 0 && c == 0) ? 0.0f : FINF;
        else if (c == 0 && bj == 0) tv = FINF;   // table col 0 sentinel
        else                        tv = rowb[(size_t)bi * MP1 + WCH2 * bj + c];
        top_s[c] = tv;
    }
    __syncthreads();

    const int c0 = WCH2 * bj + KC2 * lane;
    float yv[KC2], cur[KC2];
#pragma unroll
    for (int q = 0; q < KC2; ++q) {
        yv[q]  = y[c0 + q];
        cur[q] = top_s[KC2 * lane + q + 1];
    }
    float pl = top_s[KC2 * lane];        // diag seed for the lane's first row
    float rlast[R2];
#pragma unroll
    for (int r = 0; r < R2; ++r) rlast[r] = FINF;

    float xcur[R2];
#pragma unroll
    for (int r = 0; r < R2; ++r) xcur[r] = xb_s[r];

    int off = (BR * bi + 1 - R2 * lane) * MP1 + c0 + 1;  // out offset (t=0 row)

    for (int s = 0; s < STEPS2; ++s) {
        float vin[R2];
#pragma unroll
        for (int r = 0; r < R2; ++r) {
            const float up = shup1(rlast[r]);
            const int  li  = R2 * s + r;             // lane0's left idx (uniform)
            const float l0 = left_s[li < BR ? li : BR - 1];
            vin[r] = (lane == 0) ? l0 : up;
        }

        const int  t      = s - lane;
        const bool active = (t >= 0) && (t < TS2);
        if (active) {
            float rv[R2], rd[R2], nvm[R2][KC2];
#pragma unroll
            for (int r = 0; r < R2; ++r) rv[r] = vin[r];

#pragma unroll
            for (int d = 0; d < R2 + KC2 - 1; ++d) {
#pragma unroll
                for (int r = R2 - 1; r >= 0; --r) {
                    const int q = d - r;
                    if (q < 0 || q >= KC2) continue;
                    const float up = (r == 0) ? cur[q] : rv[r - 1];
                    const float dg = (r == 0) ? ((q == 0) ? pl : cur[q - 1])
                                              : rd[r - 1];
                    const float dx = xcur[r] - yv[q];
                    const float nv = dx * dx + fminf(fminf(up, dg), rv[r]);
                    rd[r] = rv[r];
                    rv[r] = nv;
                    nvm[r][q] = nv;
                    if (r == R2 - 1) cur[q] = nv;
                }
            }
#pragma unroll
            for (int r = 0; r < R2; ++r) rlast[r] = rv[r];
            pl = vin[R2 - 1];

#pragma unroll
            for (int r = 0; r < R2; ++r) {
                *(f4a*)(&out[off + r * MP1]) =
                    (f4a){__builtin_amdgcn_sqrtf(nvm[r][0]),
                          __builtin_amdgcn_sqrtf(nvm[r][1]),
                          __builtin_amdgcn_sqrtf(nvm[r][2]),
                          __builtin_amdgcn_sqrtf(nvm[r][3])};
                *(f4a*)(&out[off + r * MP1 + 4]) =
                    (f4a){__builtin_amdgcn_sqrtf(nvm[r][4]),
                          __builtin_amdgcn_sqrtf(nvm[r][5]),
                          __builtin_amdgcn_sqrtf(nvm[r][6]),
                          __builtin_amdgcn_sqrtf(nvm[r][7])};
            }
        }
        off += R2 * MP1;

        // ---- x for next step ----
        const int sn = s + 1;
#pragma unroll
        for (int r = 0; r < R2; ++r) {
            const float xs = shup1(xcur[r]);
            const int  xi  = R2 * sn + r;
            const float xj = xb_s[xi < BR ? xi : BR - 1];
            xcur[r] = (lane == 0) ? xj : xs;
        }
    }
}

// Row 0 / column 0 sentinels (final, sqrt'd).
__global__ void dtw_edges(float* __restrict__ out, float ev) {
    const int idx = blockIdx.x * blockDim.x + threadIdx.x;
    if (idx <= NN) {
        out[idx] = (idx == 0) ? 0.0f : ev;          // row 0
        if (idx >= 1) out[(size_t)idx * MP1] = ev;  // column 0
    }
}

extern "C" void kernel_launch(void* const* d_in, const int* in_sizes, int n_in,
                              void* d_out, int out_size, void* d_ws, size_t ws_size,
                              hipStream_t stream) {
    (void)in_sizes; (void)n_in; (void)out_size; (void)ws_size;
    const float* x = (const float*)d_in[0];
    const float* y = (const float*)d_in[1];
    float* out     = (float*)d_out;
    int* flags     = (int*)d_ws;

    const size_t bnd_off  = 4096;
    const size_t bnd_sz   = (size_t)GCH1 * NN * sizeof(float);   // 288 KB
    const size_t rowb_off = bnd_off + bnd_sz;
    float* bnd  = (float*)((char*)d_ws + bnd_off);
    float* rowb = (float*)((char*)d_ws + rowb_off);              // 16*6145*4 B

    hipMemsetAsync(flags, 0, GCH1 * 16 * sizeof(int), stream);

    dtw_edges<<<(MP1 + 255) / 256, 256, 0, stream>>>(out, sqrtf(FINF));
    dtw_bnd<<<GCH1, 64, 0, stream>>>(x, y, flags, bnd, rowb);
    dtw_tile<<<dim3(GCH1, NBI), 64, 0, stream>>>(x, y, bnd, rowb, out);
}

// Round 5
// 1686.249 us; speedup vs baseline: 1.0007x; 1.0007x over previous
//
#include <hip/hip_runtime.h>
#include <math.h>

#define NN    6144
#define MP1   6145
#define FINF  99999.0f

// ---- phase 1: boundary-only systolic chain (R=KC=8, diagonal-ILP step) ----
#define R1     8                 // rows per lane per step
#define KC1    8                 // columns per lane
#define WCH1   (KC1 * 64)        // 512 cols per wave
#define GCH1   (NN / WCH1)       // 12 strips
#define RTS1   8                 // steps per flag (= 64 boundary rows)
#define NWS1   (NN / R1)         // 768 work steps
#define STEPS1 (NWS1 + 63)       // 831 incl. lane stagger

// ---- phase 2: independent tiles (KC=8 to match 512-col strips) ----
#define R2     4
#define KC2    8
#define WCH2   (KC2 * 64)        // 512 cols per tile
#define BR     192               // rows per band
#define NBI    (NN / BR)         // 32 bands -> 384 independent tiles
#define TS2    (BR / R2)         // 48 work steps
#define STEPS2 (TS2 + 63)        // 111

typedef float f4a __attribute__((ext_vector_type(4), aligned(4)));   // unaligned-ok store
typedef float f4v __attribute__((ext_vector_type(4), aligned(16)));  // aligned vec

__device__ __forceinline__ float readlane_f(float v, int l) {
    return __int_as_float(__builtin_amdgcn_readlane(__float_as_int(v), l));
}
// lane i <- lane i-1, via DPP wave_shr:1 (VALU-speed)
__device__ __forceinline__ float shup1(float v) {
    return __int_as_float(__builtin_amdgcn_update_dpp(
        0, __float_as_int(v), 0x138, 0xF, 0xF, false));
}

// ============================ PHASE 1 ============================
// Lane-systolic DTW, 8x8 cells per lane per step, stores ONLY boundaries.
// Step body is a DIAGONAL WAVEFRONT over (r+q): chain depth 15 cells instead
// of 64. launch_bounds(64,1): we run 1 wave/CU, so give the allocator the
// full register file — R4's (64)-only build allocated 36 VGPRs and spilled
// the diagonal schedule away.
__global__ void __launch_bounds__(64, 1) dtw_bnd(const float* __restrict__ x,
                                                 const float* __restrict__ y,
                                                 int* __restrict__ flags,
                                                 float* __restrict__ bnd,
                                                 float* __restrict__ rowb) {
    const int g    = blockIdx.x;
    const int lane = threadIdx.x;
    const int c0   = g * WCH1 + lane * KC1;

    float yv[KC1], cur[KC1];
#pragma unroll
    for (int q = 0; q < KC1; ++q) {
        yv[q]  = y[c0 + q];
        cur[q] = FINF;                   // dtw[0][col] = INF
    }
    float pl = (c0 == 0) ? 0.0f : FINF;  // diag seed: dtw[0][0] = 0
    float rowval[R1];                    // right-edge carries across steps
#pragma unroll
    for (int r = 0; r < R1; ++r) rowval[r] = FINF;
    float vbuf = FINF, vnext = FINF;

    // x register window: per 64-step window w, lane m holds x[8*(64w+m) .. +7]
    const float4* x4 = (const float4*)x;
    float4 xwA  = x4[2 * lane];
    float4 xwB  = x4[2 * lane + 1];
    float4 xwAN = x4[2 * (64 + lane)];
    float4 xwBN = x4[2 * (64 + lane) + 1];
    float xcur[R1];
#pragma unroll
    for (int r = 0; r < R1; ++r) xcur[r] = x[r];

    // ---- prefetch tile 0 boundary (rows 0..63) before the loop ----
    if (g != 0) {
        while (__hip_atomic_load(&flags[(g - 1) * 16], __ATOMIC_ACQUIRE,
                                 __HIP_MEMORY_SCOPE_AGENT) < 1) {
            __builtin_amdgcn_s_sleep(1);
        }
        vnext = bnd[(size_t)(g - 1) * NN + lane];
    }

    for (int s = 0; s < STEPS1; ++s) {
        // ---- producer publish (top of step, >=1 full step of store slack) ----
        if (g != GCH1 - 1 && s > 64 && ((s - 64) & (RTS1 - 1)) == 0) {
            if (lane == 0)
                __hip_atomic_store(&flags[g * 16], (s - 64) >> 3,
                                   __ATOMIC_RELEASE, __HIP_MEMORY_SCOPE_AGENT);
        }

        // ---- consume the prefetched boundary window ----
        if (g != 0 && s < NWS1 && (s & (RTS1 - 1)) == 0) vbuf = vnext;

        // ---- prefetch next window's 64 boundary rows, 4 steps early ----
        if (g != 0 && (s & (RTS1 - 1)) == RTS1 - 4 && (s + 4) < NWS1) {
            const int want = ((s + 4) >> 3) + 1;
            while (__hip_atomic_load(&flags[(g - 1) * 16], __ATOMIC_ACQUIRE,
                                     __HIP_MEMORY_SCOPE_AGENT) < want) {
                __builtin_amdgcn_s_sleep(1);
            }
            vnext = bnd[(size_t)(g - 1) * NN + (size_t)R1 * (s + 4) + lane];
        }

        // ---- carries: DPP wave_shr1 of last step's right edges ----
        float vin[R1];
#pragma unroll
        for (int r = 0; r < R1; ++r) {
            const float up = shup1(rowval[r]);
            const float vb = readlane_f(vbuf, ((s & (RTS1 - 1)) << 3) + r);
            const float l0 = (g == 0) ? FINF : vb;
            vin[r] = (lane == 0) ? l0 : up;
        }

        const int  t      = s - lane;
        const bool active = (t >= 0) && (t < NWS1);
        if (active) {
            float rv[R1], rd[R1];
#pragma unroll
            for (int r = 0; r < R1; ++r) rv[r] = vin[r];

            // ---- diagonal wavefront: d = r + q; rows DESCENDING so row r
            // reads rv/rd[r-1] from diagonal d-1 before row r-1 updates.
#pragma unroll
            for (int d = 0; d < R1 + KC1 - 1; ++d) {
#pragma unroll
                for (int r = R1 - 1; r >= 0; --r) {
                    const int q = d - r;
                    if (q < 0 || q >= KC1) continue;
                    const float up = (r == 0) ? cur[q] : rv[r - 1];
                    const float dg = (r == 0) ? ((q == 0) ? pl : cur[q - 1])
                                              : rd[r - 1];
                    const float dx = xcur[r] - yv[q];
                    const float nv = dx * dx + fminf(fminf(up, dg), rv[r]);
                    rd[r] = rv[r];
                    rv[r] = nv;
                    if (r == R1 - 1) cur[q] = nv;   // row above for next step
                }
            }
#pragma unroll
            for (int r = 0; r < R1; ++r) rowval[r] = rv[r];
            pl = vin[R1 - 1];

            // band top rows: row 192k is r=7 of work step t=24k-1 (== cur[])
            {
                const int tp1 = t + 1;
                const int k   = tp1 / 24;
                if (k * 24 == tp1 && k >= 1 && k <= NBI - 1) {
                    *(f4a*)&rowb[(size_t)k * MP1 + c0 + 1] =
                        (f4a){cur[0], cur[1], cur[2], cur[3]};
                    *(f4a*)&rowb[(size_t)k * MP1 + c0 + 5] =
                        (f4a){cur[4], cur[5], cur[6], cur[7]};
                }
            }
            if (lane == 63) {
                *(f4v*)&bnd[(size_t)g * NN + (size_t)R1 * t] =
                    (f4v){rowval[0], rowval[1], rowval[2], rowval[3]};
                *(f4v*)&bnd[(size_t)g * NN + (size_t)R1 * t + 4] =
                    (f4v){rowval[4], rowval[5], rowval[6], rowval[7]};
            }
        }

        // ---- x for next step (off the carry chain) ----
        const int sn = s + 1;
        if ((sn & 63) == 0) {
            xwA = xwAN;
            xwB = xwBN;
            int nb = sn + 64 + lane;                 // float8-unit index
            if (nb > NN / 8 - 1) nb = NN / 8 - 1;
            xwAN = x4[2 * nb];
            xwBN = x4[2 * nb + 1];
        }
        const float* xap = (const float*)&xwA;
        const float* xbp = (const float*)&xwB;
#pragma unroll
        for (int r = 0; r < 4; ++r) {
            const float xs = shup1(xcur[r]);
            const float xj = readlane_f(xap[r], sn & 63);
            xcur[r] = (lane == 0) ? xj : xs;
        }
#pragma unroll
        for (int r = 4; r < 8; ++r) {
            const float xs = shup1(xcur[r]);
            const float xj = readlane_f(xbp[r - 4], sn & 63);
            xcur[r] = (lane == 0) ? xj : xs;
        }
    }

    // final window flag — produced by the last loop steps
    if (g != GCH1 - 1 && lane == 0) {
        __hip_atomic_store(&flags[g * 16], NWS1 >> 3,
                           __ATOMIC_RELEASE, __HIP_MEMORY_SCOPE_AGENT);
    }
}

// ============================ PHASE 2 ============================
// 384 independent 192-row x 512-col tiles seeded from bnd/rowb; same
// diagonal-wavefront step body; sqrt fused into coalesced stores to out.
__global__ void __launch_bounds__(64, 1) dtw_tile(const float* __restrict__ x,
                                                  const float* __restrict__ y,
                                                  const float* __restrict__ bnd,
                                                  const float* __restrict__ rowb,
                                                  float* __restrict__ out) {
    const int bj   = blockIdx.x;         // strip  (column block, 0..11)
    const int bi   = blockIdx.y;         // band   (row block,    0..31)
    const int lane = threadIdx.x;

    __shared__ float left_s[BR];         // left boundary col, rows +1..+192
    __shared__ float top_s[WCH2 + 1];    // top boundary row, local cols 0..512
    __shared__ float xb_s[BR];           // x for this band

#pragma unroll
    for (int k = 0; k < BR / 64; ++k) {
        const int i = 64 * k + lane;     // 0..191
        left_s[i] = (bj == 0) ? FINF
                              : bnd[(size_t)(bj - 1) * NN + BR * bi + i];
        xb_s[i] = x[BR * bi + i];
    }
    for (int c = lane; c < WCH2 + 1; c += 64) {
        float tv;
        if (bi == 0)                tv = (bj == 0 && c == 0) ? 0.0f : FINF;
        else if (c == 0 && bj == 0) tv = FINF;   // table col 0 sentinel
        else                        tv = rowb[(size_t)bi * MP1 + WCH2 * bj + c];
        top_s[c] = tv;
    }
    __syncthreads();

    const int c0 = WCH2 * bj + KC2 * lane;
    float yv[KC2], cur[KC2];
#pragma unroll
    for (int q = 0; q < KC2; ++q) {
        yv[q]  = y[c0 + q];
        cur[q] = top_s[KC2 * lane + q + 1];
    }
    float pl = top_s[KC2 * lane];        // diag seed for the lane's first row
    float rlast[R2];
#pragma unroll
    for (int r = 0; r < R2; ++r) rlast[r] = FINF;

    float xcur[R2];
#pragma unroll
    for (int r = 0; r < R2; ++r) xcur[r] = xb_s[r];

    int off = (BR * bi + 1 - R2 * lane) * MP1 + c0 + 1;  // out offset (t=0 row)

    for (int s = 0; s < STEPS2; ++s) {
        float vin[R2];
#pragma unroll
        for (int r = 0; r < R2; ++r) {
            const float up = shup1(rlast[r]);
            const int  li  = R2 * s + r;             // lane0's left idx (uniform)
            const float l0 = left_s[li < BR ? li : BR - 1];
            vin[r] = (lane == 0) ? l0 : up;
        }

        const int  t      = s - lane;
        const bool active = (t >= 0) && (t < TS2);
        if (active) {
            float rv[R2], rd[R2], nvm[R2][KC2];
#pragma unroll
            for (int r = 0; r < R2; ++r) rv[r] = vin[r];

#pragma unroll
            for (int d = 0; d < R2 + KC2 - 1; ++d) {
#pragma unroll
                for (int r = R2 - 1; r >= 0; --r) {
                    const int q = d - r;
                    if (q < 0 || q >= KC2) continue;
                    const float up = (r == 0) ? cur[q] : rv[r - 1];
                    const float dg = (r == 0) ? ((q == 0) ? pl : cur[q - 1])
                                              : rd[r - 1];
                    const float dx = xcur[r] - yv[q];
                    const float nv = dx * dx + fminf(fminf(up, dg), rv[r]);
                    rd[r] = rv[r];
                    rv[r] = nv;
                    nvm[r][q] = nv;
                    if (r == R2 - 1) cur[q] = nv;
                }
            }
#pragma unroll
            for (int r = 0; r < R2; ++r) rlast[r] = rv[r];
            pl = vin[R2 - 1];

#pragma unroll
            for (int r = 0; r < R2; ++r) {
                *(f4a*)(&out[off + r * MP1]) =
                    (f4a){__builtin_amdgcn_sqrtf(nvm[r][0]),
                          __builtin_amdgcn_sqrtf(nvm[r][1]),
                          __builtin_amdgcn_sqrtf(nvm[r][2]),
                          __builtin_amdgcn_sqrtf(nvm[r][3])};
                *(f4a*)(&out[off + r * MP1 + 4]) =
                    (f4a){__builtin_amdgcn_sqrtf(nvm[r][4]),
                          __builtin_amdgcn_sqrtf(nvm[r][5]),
                          __builtin_amdgcn_sqrtf(nvm[r][6]),
                          __builtin_amdgcn_sqrtf(nvm[r][7])};
            }
        }
        off += R2 * MP1;

        // ---- x for next step ----
        const int sn = s + 1;
#pragma unroll
        for (int r = 0; r < R2; ++r) {
            const float xs = shup1(xcur[r]);
            const int  xi  = R2 * sn + r;
            const float xj = xb_s[xi < BR ? xi : BR - 1];
            xcur[r] = (lane == 0) ? xj : xs;
        }
    }
}

// Row 0 / column 0 sentinels (final, sqrt'd).
__global__ void dtw_edges(float* __restrict__ out, float ev) {
    const int idx = blockIdx.x * blockDim.x + threadIdx.x;
    if (idx <= NN) {
        out[idx] = (idx == 0) ? 0.0f : ev;          // row 0
        if (idx >= 1) out[(size_t)idx * MP1] = ev;  // column 0
    }
}

extern "C" void kernel_launch(void* const* d_in, const int* in_sizes, int n_in,
                              void* d_out, int out_size, void* d_ws, size_t ws_size,
                              hipStream_t stream) {
    (void)in_sizes; (void)n_in; (void)out_size; (void)ws_size;
    const float* x = (const float*)d_in[0];
    const float* y = (const float*)d_in[1];
    float* out     = (float*)d_out;
    int* flags     = (int*)d_ws;

    const size_t bnd_off  = 4096;
    const size_t bnd_sz   = (size_t)GCH1 * NN * sizeof(float);   // 288 KB
    const size_t rowb_off = bnd_off + bnd_sz;
    float* bnd  = (float*)((char*)d_ws + bnd_off);
    float* rowb = (float*)((char*)d_ws + rowb_off);              // 32*6145*4 B

    hipMemsetAsync(flags, 0, GCH1 * 16 * sizeof(int), stream);

    dtw_edges<<<(MP1 + 255) / 256, 256, 0, stream>>>(out, sqrtf(FINF));
    dtw_bnd<<<GCH1, 64, 0, stream>>>(x, y, flags, bnd, rowb);
    dtw_tile<<<dim3(GCH1, NBI), 64, 0, stream>>>(x, y, bnd, rowb, out);
}

// Round 7
// 1497.778 us; speedup vs baseline: 1.1266x; 1.1258x over previous
//
#include <hip/hip_runtime.h>
#include <math.h>

#define NN    6144
#define MP1   6145
#define FINF  99999.0f

// ---- phase 1: boundary-only systolic chain (R=KC=8, diagonal-ILP step) ----
#define R1     8                 // rows per lane per step
#define KC1    8                 // columns per lane
#define WCH1   (KC1 * 64)        // 512 cols per wave
#define GCH1   (NN / WCH1)       // 12 strips
#define NWS1   (NN / R1)         // 768 work steps
#define STEPS1 (NWS1 + 63)       // 831 incl. lane stagger

// ---- phase 2: independent tiles (KC=8 to match 512-col strips) ----
#define R2     4
#define KC2    8
#define WCH2   (KC2 * 64)        // 512 cols per tile
#define BR     192               // rows per band
#define NBI    (NN / BR)         // 32 bands -> 384 independent tiles
#define TS2    (BR / R2)         // 48 work steps
#define STEPS2 (TS2 + 63)        // 111

typedef float f4a __attribute__((ext_vector_type(4), aligned(4)));   // unaligned-ok store
typedef float f4v __attribute__((ext_vector_type(4), aligned(16)));  // aligned vec

// lane i <- lane i-1 (wave_shr:1); lane 0 <- old.lane0  (bound_ctrl=false)
__device__ __forceinline__ float shr1_old(float old, float v) {
    return __int_as_float(__builtin_amdgcn_update_dpp(
        __float_as_int(old), __float_as_int(v), 0x138, 0xF, 0xF, false));
}
// lane i <- lane i+1 (wave_shl:1); lane 63 gets 0 (junk, unused)
__device__ __forceinline__ float rot_dn(float v) {
    return __int_as_float(__builtin_amdgcn_update_dpp(
        0, __float_as_int(v), 0x130, 0xF, 0xF, false));
}

// ============================ PHASE 1 ============================
// Lane-systolic DTW, 8x8 cells/lane/step, stores ONLY boundaries.
// Step body = diagonal wavefront (chain depth 15 not 64).
// waves_per_eu(1,1): pin the scheduler's register budget to 1-wave occupancy.
// Carries: boundary/x values injected through the DPP 'old' operand of
// rotating registers (vrow/xrow) — no readlane/cndmask/lane0-branch.
// R6 BUGFIX 1: vrow<-vnrow swap is now unconditional on g — for g==0, vnrow
//   stays all-FINF (never rotated), so lane0's col-0 sentinel never drains
//   to 0 (R6 leaked 0.0 into strip 0 after step 64 -> absmax 201).
// R6 BUGFIX 2: the early flag probe is an ACQUIRE load (relaxed probe could
//   let bnd reads skip the acquire ordering entirely).
__global__ __launch_bounds__(64) __attribute__((amdgpu_waves_per_eu(1, 1)))
void dtw_bnd(const float* __restrict__ x,
             const float* __restrict__ y,
             int* __restrict__ flags,
             float* __restrict__ bnd,
             float* __restrict__ rowb) {
    const int g    = blockIdx.x;
    const int lane = threadIdx.x;
    const int c0   = g * WCH1 + lane * KC1;

    float yv[KC1], cur[KC1];
#pragma unroll
    for (int q = 0; q < KC1; ++q) {
        yv[q]  = y[c0 + q];
        cur[q] = FINF;                   // dtw[0][col] = INF
    }
    float pl = (c0 == 0) ? 0.0f : FINF;  // diag seed: dtw[0][0] = 0
    float rowval[R1];                    // right-edge carries across steps
#pragma unroll
    for (int r = 0; r < R1; ++r) rowval[r] = FINF;

    // rotating boundary regs: vrow[r].lane0 = left-boundary row for current
    // step. vnrow holds the next tile's 64 rows (lane j = row 8j+r of tile).
    // vnrow is NEVER rotated; for g==0 it stays all-FINF.
    float vrow[R1], vnrow[R1];
#pragma unroll
    for (int r = 0; r < R1; ++r) { vrow[r] = FINF; vnrow[r] = FINF; }

    // rotating x regs: xrow[r].lane0 = x[8*sn + r] at end of step sn-1.
    float xcur[R1], xrow[R1];
#pragma unroll
    for (int r = 0; r < R1; ++r) {
        xcur[r] = x[r];
        int tt = lane + 1; if (tt > NWS1 - 1) tt = NWS1 - 1;
        xrow[r] = x[(tt << 3) + r];
    }

    int fcache = 0;

    // ---- tile 0 boundary before the loop ----
    if (g != 0) {
        while ((fcache = __hip_atomic_load(&flags[(g - 1) * 16], __ATOMIC_ACQUIRE,
                                           __HIP_MEMORY_SCOPE_AGENT)) < 1) {
            __builtin_amdgcn_s_sleep(1);
        }
        const float* bb = bnd + (size_t)(g - 1) * NN;
#pragma unroll
        for (int r = 0; r < R1; ++r) vnrow[r] = bb[(lane << 3) + r];
    }

    auto step = [&](const int s, const bool chk) {
        // ---- producer publish (>=2 steps of store slack) ----
        if (g != GCH1 - 1 && s > 64 && ((s - 64) & 7) == 0) {
            if (lane == 0)
                __hip_atomic_store(&flags[g * 16], (s - 64) >> 3,
                                   __ATOMIC_RELEASE, __HIP_MEMORY_SCOPE_AGENT);
        }
        // ---- tile start: swap in (pre)fetched boundary regs — ALL g ----
        if (s < NWS1 && (s & 7) == 0) {
#pragma unroll
            for (int r = 0; r < R1; ++r) vrow[r] = vnrow[r];
        }
        // ---- early acquire flag check, 2 steps before the prefetch ----
        if (g != 0 && (s & 7) == 2 && (s + 6) < NWS1) {
            const int want = ((s + 6) >> 3) + 1;
            if (fcache < want)
                fcache = __hip_atomic_load(&flags[(g - 1) * 16], __ATOMIC_ACQUIRE,
                                           __HIP_MEMORY_SCOPE_AGENT);
        }
        // ---- prefetch next tile's boundary rows ----
        if (g != 0 && (s & 7) == 4 && (s + 4) < NWS1) {
            const int want = ((s + 4) >> 3) + 1;
            while (fcache < want) {
                fcache = __hip_atomic_load(&flags[(g - 1) * 16], __ATOMIC_ACQUIRE,
                                           __HIP_MEMORY_SCOPE_AGENT);
                if (fcache < want) __builtin_amdgcn_s_sleep(1);
            }
            const float* bb = bnd + (size_t)(g - 1) * NN + ((size_t)(s + 4) << 3);
#pragma unroll
            for (int r = 0; r < R1; ++r) vnrow[r] = bb[(lane << 3) + r];
        }

        // ---- carries: single DPP merges chain-shift and boundary inject ----
        float vin[R1];
#pragma unroll
        for (int r = 0; r < R1; ++r) {
            vin[r]  = shr1_old(vrow[r], rowval[r]);
            vrow[r] = rot_dn(vrow[r]);
        }

        const int  t      = s - lane;
        const bool active = chk ? (t >= 0 && t < NWS1) : true;
        if (active) {
            float rv[R1], rd[R1];
#pragma unroll
            for (int r = 0; r < R1; ++r) rv[r] = vin[r];

            // diagonal wavefront d = r+q; rows DESCENDING within a diagonal.
#pragma unroll
            for (int d = 0; d < R1 + KC1 - 1; ++d) {
#pragma unroll
                for (int r = R1 - 1; r >= 0; --r) {
                    const int q = d - r;
                    if (q < 0 || q >= KC1) continue;
                    const float up = (r == 0) ? cur[q] : rv[r - 1];
                    const float dg = (r == 0) ? ((q == 0) ? pl : cur[q - 1])
                                              : rd[r - 1];
                    const float dx = xcur[r] - yv[q];
                    const float nv = dx * dx + fminf(fminf(up, dg), rv[r]);
                    rd[r] = rv[r];
                    rv[r] = nv;
                    if (r == R1 - 1) cur[q] = nv;   // row above for next step
                }
            }
#pragma unroll
            for (int r = 0; r < R1; ++r) rowval[r] = rv[r];
            pl = vin[R1 - 1];

            // band top rows: row 192k is r=7 of work step t=24k-1 (== cur[])
            {
                const int tp1 = t + 1;
                const int k   = tp1 / 24;
                if (k * 24 == tp1 && k >= 1 && k <= NBI - 1) {
                    *(f4a*)&rowb[(size_t)k * MP1 + c0 + 1] =
                        (f4a){cur[0], cur[1], cur[2], cur[3]};
                    *(f4a*)&rowb[(size_t)k * MP1 + c0 + 5] =
                        (f4a){cur[4], cur[5], cur[6], cur[7]};
                }
            }
            if (lane == 63) {
                *(f4v*)&bnd[(size_t)g * NN + (size_t)R1 * t] =
                    (f4v){rowval[0], rowval[1], rowval[2], rowval[3]};
                *(f4v*)&bnd[(size_t)g * NN + (size_t)R1 * t + 4] =
                    (f4v){rowval[4], rowval[5], rowval[6], rowval[7]};
            }
        }

        // ---- x feed for next step (same DPP-old trick) ----
        const int sn = s + 1;
        if ((sn & 63) == 0) {
#pragma unroll
            for (int r = 0; r < R1; ++r) {
                int tt = sn + lane; if (tt > NWS1 - 1) tt = NWS1 - 1;
                xrow[r] = x[(tt << 3) + r];
            }
        }
#pragma unroll
        for (int r = 0; r < R1; ++r) {
            xcur[r] = shr1_old(xrow[r], xcur[r]);
            xrow[r] = rot_dn(xrow[r]);
        }
    };

    for (int s = 0; s < 63; ++s)          step(s, true);   // fill
    for (int s = 63; s < NWS1; ++s)       step(s, false);  // steady: all active
    for (int s = NWS1; s < STEPS1; ++s)   step(s, true);   // drain

    // final flag — rows through 6144 complete
    if (g != GCH1 - 1 && lane == 0) {
        __hip_atomic_store(&flags[g * 16], NWS1 >> 3,
                           __ATOMIC_RELEASE, __HIP_MEMORY_SCOPE_AGENT);
    }
}

// ============================ PHASE 2 ============================
// 384 independent 192x512 tiles seeded from bnd/rowb; diagonal body; left
// boundary and x fed by rotating DPP regs (consumed only for s<48<64, so no
// drain hazard); sqrt fused into coalesced stores to out.
__global__ __launch_bounds__(64) __attribute__((amdgpu_waves_per_eu(1, 1)))
void dtw_tile(const float* __restrict__ x,
              const float* __restrict__ y,
              const float* __restrict__ bnd,
              const float* __restrict__ rowb,
              float* __restrict__ out) {
    const int bj   = blockIdx.x;         // strip  (column block, 0..11)
    const int bi   = blockIdx.y;         // band   (row block,    0..31)
    const int lane = threadIdx.x;

    __shared__ float top_s[WCH2 + 1];    // top boundary row, local cols 0..512
    for (int c = lane; c < WCH2 + 1; c += 64) {
        float tv;
        if (bi == 0)                tv = (bj == 0 && c == 0) ? 0.0f : FINF;
        else if (c == 0 && bj == 0) tv = FINF;   // table col 0 sentinel
        else                        tv = rowb[(size_t)bi * MP1 + WCH2 * bj + c];
        top_s[c] = tv;
    }

    // rotating left-boundary regs: lane j (orig) = left row 4j+r
    float lrow[R2];
    const float* lb = bnd + (size_t)(bj - 1) * NN + (size_t)BR * bi;
#pragma unroll
    for (int r = 0; r < R2; ++r) {
        int li = 4 * lane + r; if (li > BR - 1) li = BR - 1;
        lrow[r] = (bj == 0) ? FINF : lb[li];
    }
    // rotating x regs
    float xcur[R2], xr2[R2];
    const float* xb = x + BR * bi;
#pragma unroll
    for (int r = 0; r < R2; ++r) {
        xcur[r] = xb[r];
        int xi = 4 * (lane + 1) + r; if (xi > BR - 1) xi = BR - 1;
        xr2[r] = xb[xi];
    }
    __syncthreads();

    const int c0 = WCH2 * bj + KC2 * lane;
    float yv[KC2], cur[KC2];
#pragma unroll
    for (int q = 0; q < KC2; ++q) {
        yv[q]  = y[c0 + q];
        cur[q] = top_s[KC2 * lane + q + 1];
    }
    float pl = top_s[KC2 * lane];        // diag seed for the lane's first row
    float rlast[R2];
#pragma unroll
    for (int r = 0; r < R2; ++r) rlast[r] = FINF;

    int off = (BR * bi + 1 - R2 * lane) * MP1 + c0 + 1;  // out offset (t=0 row)

    for (int s = 0; s < STEPS2; ++s) {
        float vin[R2];
#pragma unroll
        for (int r = 0; r < R2; ++r) {
            vin[r]  = shr1_old(lrow[r], rlast[r]);
            lrow[r] = rot_dn(lrow[r]);
        }

        const int  t      = s - lane;
        const bool active = (t >= 0) && (t < TS2);
        if (active) {
            float rv[R2], rd[R2], nvm[R2][KC2];
#pragma unroll
            for (int r = 0; r < R2; ++r) rv[r] = vin[r];

#pragma unroll
            for (int d = 0; d < R2 + KC2 - 1; ++d) {
#pragma unroll
                for (int r = R2 - 1; r >= 0; --r) {
                    const int q = d - r;
                    if (q < 0 || q >= KC2) continue;
                    const float up = (r == 0) ? cur[q] : rv[r - 1];
                    const float dg = (r == 0) ? ((q == 0) ? pl : cur[q - 1])
                                              : rd[r - 1];
                    const float dx = xcur[r] - yv[q];
                    const float nv = dx * dx + fminf(fminf(up, dg), rv[r]);
                    rd[r] = rv[r];
                    rv[r] = nv;
                    nvm[r][q] = nv;
                    if (r == R2 - 1) cur[q] = nv;
                }
            }
#pragma unroll
            for (int r = 0; r < R2; ++r) rlast[r] = rv[r];
            pl = vin[R2 - 1];

#pragma unroll
            for (int r = 0; r < R2; ++r) {
                *(f4a*)(&out[off + r * MP1]) =
                    (f4a){__builtin_amdgcn_sqrtf(nvm[r][0]),
                          __builtin_amdgcn_sqrtf(nvm[r][1]),
                          __builtin_amdgcn_sqrtf(nvm[r][2]),
                          __builtin_amdgcn_sqrtf(nvm[r][3])};
                *(f4a*)(&out[off + r * MP1 + 4]) =
                    (f4a){__builtin_amdgcn_sqrtf(nvm[r][4]),
                          __builtin_amdgcn_sqrtf(nvm[r][5]),
                          __builtin_amdgcn_sqrtf(nvm[r][6]),
                          __builtin_amdgcn_sqrtf(nvm[r][7])};
            }
        }
        off += R2 * MP1;

        // ---- x feed for next step ----
#pragma unroll
        for (int r = 0; r < R2; ++r) {
            xcur[r] = shr1_old(xr2[r], xcur[r]);
            xr2[r]  = rot_dn(xr2[r]);
        }
    }
}

// Row 0 / column 0 sentinels (final, sqrt'd).
__global__ void dtw_edges(float* __restrict__ out, float ev) {
    const int idx = blockIdx.x * blockDim.x + threadIdx.x;
    if (idx <= NN) {
        out[idx] = (idx == 0) ? 0.0f : ev;          // row 0
        if (idx >= 1) out[(size_t)idx * MP1] = ev;  // column 0
    }
}

extern "C" void kernel_launch(void* const* d_in, const int* in_sizes, int n_in,
                              void* d_out, int out_size, void* d_ws, size_t ws_size,
                              hipStream_t stream) {
    (void)in_sizes; (void)n_in; (void)out_size; (void)ws_size;
    const float* x = (const float*)d_in[0];
    const float* y = (const float*)d_in[1];
    float* out     = (float*)d_out;
    int* flags     = (int*)d_ws;

    const size_t bnd_off  = 4096;
    const size_t bnd_sz   = (size_t)GCH1 * NN * sizeof(float);   // 288 KB
    const size_t rowb_off = bnd_off + bnd_sz;
    float* bnd  = (float*)((char*)d_ws + bnd_off);
    float* rowb = (float*)((char*)d_ws + rowb_off);              // 32*6145*4 B

    hipMemsetAsync(flags, 0, GCH1 * 16 * sizeof(int), stream);

    dtw_edges<<<(MP1 + 255) / 256, 256, 0, stream>>>(out, sqrtf(FINF));
    dtw_bnd<<<GCH1, 64, 0, stream>>>(x, y, flags, bnd, rowb);
    dtw_tile<<<dim3(GCH1, NBI), 64, 0, stream>>>(x, y, bnd, rowb, out);
}

// Round 8
// 1458.673 us; speedup vs baseline: 1.1568x; 1.0268x over previous
//
#include <hip/hip_runtime.h>
#include <math.h>

#define NN    6144
#define MP1   6145
#define FINF  99999.0f

// ---- phase 1: boundary-only systolic chain (R=KC=8, diagonal-ILP step) ----
#define R1     8                 // rows per lane per step
#define KC1    8                 // columns per lane
#define WCH1   (KC1 * 64)        // 512 cols per wave
#define GCH1   (NN / WCH1)       // 12 strips
#define NWS1   (NN / R1)         // 768 work steps
#define STEPS1 (NWS1 + 63)       // 831 incl. lane stagger

// ---- phase 2: independent tiles (KC=8 to match 512-col strips) ----
#define R2     4
#define KC2    8
#define WCH2   (KC2 * 64)        // 512 cols per tile
#define BR     192               // rows per band
#define NBI    (NN / BR)         // 32 bands -> 384 independent tiles
#define TS2    (BR / R2)         // 48 work steps
#define STEPS2 (TS2 + 63)        // 111

typedef float f4a __attribute__((ext_vector_type(4), aligned(4)));   // unaligned-ok store
typedef float f4v __attribute__((ext_vector_type(4), aligned(16)));  // aligned vec

// lane i <- lane i-1 (wave_shr:1); lane 0 <- old.lane0  (bound_ctrl=false)
__device__ __forceinline__ float shr1_old(float old, float v) {
    return __int_as_float(__builtin_amdgcn_update_dpp(
        __float_as_int(old), __float_as_int(v), 0x138, 0xF, 0xF, false));
}
// lane i <- lane i+1 (wave_shl:1); lane 63 gets 0 (junk, unused)
__device__ __forceinline__ float rot_dn(float v) {
    return __int_as_float(__builtin_amdgcn_update_dpp(
        0, __float_as_int(v), 0x130, 0xF, 0xF, false));
}
// 3-input min in ONE VALU op (gfx950 v_min3_f32)
__device__ __forceinline__ float min3f(float a, float b, float c) {
    float r;
    asm("v_min3_f32 %0, %1, %2, %3" : "=v"(r) : "v"(a), "v"(b), "v"(c));
    return r;
}

// ============================ PHASE 1 ============================
// Lane-systolic DTW, 8x8 cells/lane/step, stores ONLY boundaries.
// Step body = diagonal wavefront; per-cell = {v_sub, v_min3, v_fma} (3 VALU).
// x feed = per-step dwordx4 loads (L1-resident), issued 1 step ahead —
// replaces 16 DPP/step of rotating-register machinery.
// rowb firing tracked by a mod-24 lane counter + bumped pointer (no division).
__global__ __launch_bounds__(64) __attribute__((amdgpu_waves_per_eu(1, 1)))
void dtw_bnd(const float* __restrict__ x,
             const float* __restrict__ y,
             int* __restrict__ flags,
             float* __restrict__ bnd,
             float* __restrict__ rowb) {
    const int g    = blockIdx.x;
    const int lane = threadIdx.x;
    const int c0   = g * WCH1 + lane * KC1;

    float yv[KC1], cur[KC1];
#pragma unroll
    for (int q = 0; q < KC1; ++q) {
        yv[q]  = y[c0 + q];
        cur[q] = FINF;                   // dtw[0][col] = INF
    }
    float pl = (c0 == 0) ? 0.0f : FINF;  // diag seed: dtw[0][0] = 0
    float rowval[R1];                    // right-edge carries across steps
#pragma unroll
    for (int r = 0; r < R1; ++r) rowval[r] = FINF;

    // rotating boundary regs: vrow[r].lane0 = left-boundary row for current
    // step. vnrow holds the next tile's rows (never rotated; g==0: all-FINF).
    float vrow[R1], vnrow[R1];
#pragma unroll
    for (int r = 0; r < R1; ++r) { vrow[r] = FINF; vnrow[r] = FINF; }

    // x for the current step: lane L at step s uses x[8*(s-L) .. +7]
    float xcur[R1];
#pragma unroll
    for (int r = 0; r < R1; ++r) xcur[r] = x[r];   // t clamped to 0

    // rowb firing: vcnt == (s+1-lane) mod 24; fire when 0 (and t in range)
    int vcnt = ((1 - lane) % 24 + 24) % 24;
    float* rp = rowb + (size_t)MP1 + c0 + 1;       // k=1 target, bumped per fire

    int fcache = 0;

    // ---- tile 0 boundary before the loop ----
    if (g != 0) {
        while ((fcache = __hip_atomic_load(&flags[(g - 1) * 16], __ATOMIC_ACQUIRE,
                                           __HIP_MEMORY_SCOPE_AGENT)) < 1) {
            __builtin_amdgcn_s_sleep(1);
        }
        const float* bb = bnd + (size_t)(g - 1) * NN;
#pragma unroll
        for (int r = 0; r < R1; ++r) vnrow[r] = bb[(lane << 3) + r];
    }

    auto step = [&](const int s, const bool chk) {
        // ---- x loads for NEXT step (issued first; waited at step end) ----
        int tn = s + 1 - lane;
        if (tn < 0) tn = 0;
        if (tn > NWS1 - 1) tn = NWS1 - 1;
        const float4* xp = (const float4*)(x + ((size_t)tn << 3));
        const float4 xnA = xp[0];
        const float4 xnB = xp[1];

        // ---- producer publish (>=2 steps of store slack) ----
        if (g != GCH1 - 1 && s > 64 && ((s - 64) & 7) == 0) {
            if (lane == 0)
                __hip_atomic_store(&flags[g * 16], (s - 64) >> 3,
                                   __ATOMIC_RELEASE, __HIP_MEMORY_SCOPE_AGENT);
        }
        // ---- tile start: swap in (pre)fetched boundary regs — ALL g ----
        if (s < NWS1 && (s & 7) == 0) {
#pragma unroll
            for (int r = 0; r < R1; ++r) vrow[r] = vnrow[r];
        }
        // ---- early acquire flag check, 2 steps before the prefetch ----
        if (g != 0 && (s & 7) == 2 && (s + 6) < NWS1) {
            const int want = ((s + 6) >> 3) + 1;
            if (fcache < want)
                fcache = __hip_atomic_load(&flags[(g - 1) * 16], __ATOMIC_ACQUIRE,
                                           __HIP_MEMORY_SCOPE_AGENT);
        }
        // ---- prefetch next tile's boundary rows ----
        if (g != 0 && (s & 7) == 4 && (s + 4) < NWS1) {
            const int want = ((s + 4) >> 3) + 1;
            while (fcache < want) {
                fcache = __hip_atomic_load(&flags[(g - 1) * 16], __ATOMIC_ACQUIRE,
                                           __HIP_MEMORY_SCOPE_AGENT);
                if (fcache < want) __builtin_amdgcn_s_sleep(1);
            }
            const float* bb = bnd + (size_t)(g - 1) * NN + ((size_t)(s + 4) << 3);
#pragma unroll
            for (int r = 0; r < R1; ++r) vnrow[r] = bb[(lane << 3) + r];
        }

        // ---- carries: single DPP merges chain-shift and boundary inject ----
        float vin[R1];
#pragma unroll
        for (int r = 0; r < R1; ++r) {
            vin[r]  = shr1_old(vrow[r], rowval[r]);
            vrow[r] = rot_dn(vrow[r]);
        }

        const int  t      = s - lane;
        const bool active = chk ? (t >= 0 && t < NWS1) : true;
        if (active) {
            float rv[R1], rd[R1];
#pragma unroll
            for (int r = 0; r < R1; ++r) rv[r] = vin[r];

            // diagonal wavefront d = r+q; rows DESCENDING within a diagonal.
#pragma unroll
            for (int d = 0; d < R1 + KC1 - 1; ++d) {
#pragma unroll
                for (int r = R1 - 1; r >= 0; --r) {
                    const int q = d - r;
                    if (q < 0 || q >= KC1) continue;
                    const float up = (r == 0) ? cur[q] : rv[r - 1];
                    const float dg = (r == 0) ? ((q == 0) ? pl : cur[q - 1])
                                              : rd[r - 1];
                    const float dx = xcur[r] - yv[q];
                    const float nv = fmaf(dx, dx, min3f(up, dg, rv[r]));
                    rd[r] = rv[r];
                    rv[r] = nv;
                    if (r == R1 - 1) cur[q] = nv;   // row above for next step
                }
            }
#pragma unroll
            for (int r = 0; r < R1; ++r) rowval[r] = rv[r];
            pl = vin[R1 - 1];

            // band top rows: fire when (t+1) % 24 == 0, excluding t = NWS1-1
            if (vcnt == 0 && t < NWS1 - 1) {
                *(f4a*)rp       = (f4a){cur[0], cur[1], cur[2], cur[3]};
                *(f4a*)(rp + 4) = (f4a){cur[4], cur[5], cur[6], cur[7]};
                rp += MP1;
            }
            if (lane == 63) {
                *(f4v*)&bnd[(size_t)g * NN + (size_t)R1 * t] =
                    (f4v){rowval[0], rowval[1], rowval[2], rowval[3]};
                *(f4v*)&bnd[(size_t)g * NN + (size_t)R1 * t + 4] =
                    (f4v){rowval[4], rowval[5], rowval[6], rowval[7]};
            }
        }
        vcnt = (vcnt == 23) ? 0 : vcnt + 1;

        // ---- x for next step lands here (implicit vmcnt wait) ----
        xcur[0] = xnA.x; xcur[1] = xnA.y; xcur[2] = xnA.z; xcur[3] = xnA.w;
        xcur[4] = xnB.x; xcur[5] = xnB.y; xcur[6] = xnB.z; xcur[7] = xnB.w;
    };

    for (int s = 0; s < 63; ++s)          step(s, true);   // fill
    for (int s = 63; s < NWS1; ++s)       step(s, false);  // steady: all active
    for (int s = NWS1; s < STEPS1; ++s)   step(s, true);   // drain

    // final flag — rows through 6144 complete
    if (g != GCH1 - 1 && lane == 0) {
        __hip_atomic_store(&flags[g * 16], NWS1 >> 3,
                           __ATOMIC_RELEASE, __HIP_MEMORY_SCOPE_AGENT);
    }
}

// ============================ PHASE 2 ============================
// 384 independent 192x512 tiles seeded from bnd/rowb; diagonal body; left
// boundary via rotating DPP regs; x via per-step dwordx4 loads; sqrt fused.
__global__ __launch_bounds__(64) __attribute__((amdgpu_waves_per_eu(1, 1)))
void dtw_tile(const float* __restrict__ x,
              const float* __restrict__ y,
              const float* __restrict__ bnd,
              const float* __restrict__ rowb,
              float* __restrict__ out) {
    const int bj   = blockIdx.x;         // strip  (column block, 0..11)
    const int bi   = blockIdx.y;         // band   (row block,    0..31)
    const int lane = threadIdx.x;

    __shared__ float top_s[WCH2 + 1];    // top boundary row, local cols 0..512
    for (int c = lane; c < WCH2 + 1; c += 64) {
        float tv;
        if (bi == 0)                tv = (bj == 0 && c == 0) ? 0.0f : FINF;
        else if (c == 0 && bj == 0) tv = FINF;   // table col 0 sentinel
        else                        tv = rowb[(size_t)bi * MP1 + WCH2 * bj + c];
        top_s[c] = tv;
    }

    // rotating left-boundary regs: lane j (orig) = left row 4j+r
    float lrow[R2];
    const float* lb = bnd + (size_t)(bj - 1) * NN + (size_t)BR * bi;
#pragma unroll
    for (int r = 0; r < R2; ++r) {
        int li = 4 * lane + r; if (li > BR - 1) li = BR - 1;
        lrow[r] = (bj == 0) ? FINF : lb[li];
    }
    // x for current step
    const float* xb = x + BR * bi;
    float xcur[R2];
#pragma unroll
    for (int r = 0; r < R2; ++r) xcur[r] = xb[r];  // t clamped to 0
    __syncthreads();

    const int c0 = WCH2 * bj + KC2 * lane;
    float yv[KC2], cur[KC2];
#pragma unroll
    for (int q = 0; q < KC2; ++q) {
        yv[q]  = y[c0 + q];
        cur[q] = top_s[KC2 * lane + q + 1];
    }
    float pl = top_s[KC2 * lane];        // diag seed for the lane's first row
    float rlast[R2];
#pragma unroll
    for (int r = 0; r < R2; ++r) rlast[r] = FINF;

    int off = (BR * bi + 1 - R2 * lane) * MP1 + c0 + 1;  // out offset (t=0 row)

    for (int s = 0; s < STEPS2; ++s) {
        // x loads for next step (issued first; waited at loop bottom)
        int tn = s + 1 - lane;
        if (tn < 0) tn = 0;
        if (tn > TS2 - 1) tn = TS2 - 1;
        const float4 xn = *(const float4*)(xb + ((size_t)tn << 2));

        float vin[R2];
#pragma unroll
        for (int r = 0; r < R2; ++r) {
            vin[r]  = shr1_old(lrow[r], rlast[r]);
            lrow[r] = rot_dn(lrow[r]);
        }

        const int  t      = s - lane;
        const bool active = (t >= 0) && (t < TS2);
        if (active) {
            float rv[R2], rd[R2], nvm[R2][KC2];
#pragma unroll
            for (int r = 0; r < R2; ++r) rv[r] = vin[r];

#pragma unroll
            for (int d = 0; d < R2 + KC2 - 1; ++d) {
#pragma unroll
                for (int r = R2 - 1; r >= 0; --r) {
                    const int q = d - r;
                    if (q < 0 || q >= KC2) continue;
                    const float up = (r == 0) ? cur[q] : rv[r - 1];
                    const float dg = (r == 0) ? ((q == 0) ? pl : cur[q - 1])
                                              : rd[r - 1];
                    const float dx = xcur[r] - yv[q];
                    const float nv = fmaf(dx, dx, min3f(up, dg, rv[r]));
                    rd[r] = rv[r];
                    rv[r] = nv;
                    nvm[r][q] = nv;
                    if (r == R2 - 1) cur[q] = nv;
                }
            }
#pragma unroll
            for (int r = 0; r < R2; ++r) rlast[r] = rv[r];
            pl = vin[R2 - 1];

#pragma unroll
            for (int r = 0; r < R2; ++r) {
                *(f4a*)(&out[off + r * MP1]) =
                    (f4a){__builtin_amdgcn_sqrtf(nvm[r][0]),
                          __builtin_amdgcn_sqrtf(nvm[r][1]),
                          __builtin_amdgcn_sqrtf(nvm[r][2]),
                          __builtin_amdgcn_sqrtf(nvm[r][3])};
                *(f4a*)(&out[off + r * MP1 + 4]) =
                    (f4a){__builtin_amdgcn_sqrtf(nvm[r][4]),
                          __builtin_amdgcn_sqrtf(nvm[r][5]),
                          __builtin_amdgcn_sqrtf(nvm[r][6]),
                          __builtin_amdgcn_sqrtf(nvm[r][7])};
            }
        }
        off += R2 * MP1;

        // x for next step lands here
        xcur[0] = xn.x; xcur[1] = xn.y; xcur[2] = xn.z; xcur[3] = xn.w;
    }
}

// Row 0 / column 0 sentinels (final, sqrt'd).
__global__ void dtw_edges(float* __restrict__ out, float ev) {
    const int idx = blockIdx.x * blockDim.x + threadIdx.x;
    if (idx <= NN) {
        out[idx] = (idx == 0) ? 0.0f : ev;          // row 0
        if (idx >= 1) out[(size_t)idx * MP1] = ev;  // column 0
    }
}

extern "C" void kernel_launch(void* const* d_in, const int* in_sizes, int n_in,
                              void* d_out, int out_size, void* d_ws, size_t ws_size,
                              hipStream_t stream) {
    (void)in_sizes; (void)n_in; (void)out_size; (void)ws_size;
    const float* x = (const float*)d_in[0];
    const float* y = (const float*)d_in[1];
    float* out     = (float*)d_out;
    int* flags     = (int*)d_ws;

    const size_t bnd_off  = 4096;
    const size_t bnd_sz   = (size_t)GCH1 * NN * sizeof(float);   // 288 KB
    const size_t rowb_off = bnd_off + bnd_sz;
    float* bnd  = (float*)((char*)d_ws + bnd_off);
    float* rowb = (float*)((char*)d_ws + rowb_off);              // 32*6145*4 B

    hipMemsetAsync(flags, 0, GCH1 * 16 * sizeof(int), stream);

    dtw_edges<<<(MP1 + 255) / 256, 256, 0, stream>>>(out, sqrtf(FINF));
    dtw_bnd<<<GCH1, 64, 0, stream>>>(x, y, flags, bnd, rowb);
    dtw_tile<<<dim3(GCH1, NBI), 64, 0, stream>>>(x, y, bnd, rowb, out);
}